// Round 10
// baseline (345.050 us; speedup 1.0000x reference)
//
#include <hip/hip_runtime.h>

#define N_NODES 100000
#define N_EDGES 3200000
#define D_FEAT  128

#define RPB 128                              // rows per bucket (row >> 7)
#define NB ((N_NODES + RPB - 1) / RPB)       // 782 buckets
#define P3_THREADS 512
#define P3_EPT 16                            // edges per thread in partition
#define P3_TILE (P3_THREADS * P3_EPT)        // 8192 edges per partition block
#define P3_GRID ((N_EDGES + P3_TILE - 1) / P3_TILE)   // 391

#define NS 25                                // col slices (col >> 12, 1MB bf16 each)
#define NCELL (RPB * NS)                     // 3200 sort cells per bucket
#define NCELLG ((size_t)NB * RPB * NS)       // global cell array (covers padded rows)
#define CAP 4608                             // LDS staging cap (bucket max ~4326 @8sigma)

#define CVT_BLOCKS 2048
#define HIST_BLOCKS 512

// ---------------------------------------------------------------------------
// Pipeline (R10):
//   0) cvt_bhist (FUSED): blocks [0,2048) convert x -> packed bf16; blocks
//      [2048,2560) read rows+cols, build bucket hist (LDS) AND the global
//      per-(row,colslice) cellhist (2.5M bins, low-contention atomics).
//   1) bscan: exclusive scan of NB bucket counts.
//   2) partition: counting-partition into 128-row buckets; rows reg-cached
//      across count/place phases (no rows re-read).
//   3) sort_spmm<PRE>: one 1024-thr block per bucket. PRE=1: read the 3200
//      precomputed cell counts (coalesced), scan, scatter pairs into LDS
//      sorted by (row, colslice), then SpMM (16-lane group per row, LDS
//      same-addr broadcast, f32 reg accum, one 512B row write). No Pass A.
// R6-R9 lesson: spmm is fabric-throughput-bound (~3.5 TB/s on L2-miss path);
// slice-sort buys ~53% L2 hit; remaining levers are overhead removal.
// ---------------------------------------------------------------------------

__device__ inline unsigned bf16rne(float f) {
    unsigned u = __float_as_uint(f);
    u += 0x7fffu + ((u >> 16) & 1u);
    return u >> 16;
}
__device__ inline unsigned pack2(float lo, float hi) {
    return bf16rne(lo) | (bf16rne(hi) << 16);
}

// P0: fused x->bf16 convert + bucket hist + global cell hist.
__global__ __launch_bounds__(256) void cvt_bhist_kernel(
    const float* __restrict__ x, uint4* __restrict__ xb,
    const int* __restrict__ adj_rows, const int* __restrict__ adj_cols,
    const int* __restrict__ idx_p,
    int* __restrict__ bhist, int* __restrict__ cellhist)
{
    __shared__ int lh[NB];
    if (blockIdx.x < CVT_BLOCKS) {
        const int total = N_NODES * D_FEAT / 8;
        for (int i = blockIdx.x * 256 + threadIdx.x; i < total;
             i += CVT_BLOCKS * 256) {
            const float4 a = reinterpret_cast<const float4*>(x)[2 * i];
            const float4 b = reinterpret_cast<const float4*>(x)[2 * i + 1];
            uint4 o;
            o.x = pack2(a.x, a.y);
            o.y = pack2(a.z, a.w);
            o.z = pack2(b.x, b.y);
            o.w = pack2(b.z, b.w);
            xb[i] = o;
        }
    } else {
        for (int i = threadIdx.x; i < NB; i += 256) lh[i] = 0;
        __syncthreads();
        const long long idx = (long long)idx_p[0];
        const int* rows = adj_rows + idx * (long long)N_EDGES;
        const int* cols = adj_cols + idx * (long long)N_EDGES;
        for (int e = (blockIdx.x - CVT_BLOCKS) * 256 + threadIdx.x;
             e < N_EDGES; e += HIST_BLOCKS * 256) {
            const int r = rows[e];
            atomicAdd(&lh[r >> 7], 1);
            if (cellhist)
                atomicAdd(&cellhist[(size_t)r * NS + (cols[e] >> 12)], 1);
        }
        __syncthreads();
        for (int i = threadIdx.x; i < NB; i += 256)
            if (lh[i]) atomicAdd(&bhist[i], lh[i]);
    }
}

// P1: exclusive scan of NB bucket counts (single block), init cursors.
__global__ __launch_bounds__(1024) void bscan_kernel(
    const int* __restrict__ bhist, int* __restrict__ bptr,
    int* __restrict__ bcursor)
{
    __shared__ int lds[1024];
    const int t = threadIdx.x;
    const int v = (t < NB) ? bhist[t] : 0;
    lds[t] = v;
    __syncthreads();
    for (int off = 1; off < 1024; off <<= 1) {
        int u = (t >= off) ? lds[t - off] : 0;
        __syncthreads();
        lds[t] += u;
        __syncthreads();
    }
    if (t < NB) {
        const int excl = lds[t] - v;
        bptr[t]    = excl;
        bcursor[t] = excl;
    }
    if (t == NB - 1) bptr[NB] = lds[t];
}

// P2: partition edges into buckets; rows cached in registers across phases.
__global__ __launch_bounds__(P3_THREADS) void partition_kernel(
    const int* __restrict__ adj_rows, const int* __restrict__ adj_cols,
    const float* __restrict__ adj_vals, const int* __restrict__ idx_p,
    int* __restrict__ bcursor, int2* __restrict__ pairs)
{
    __shared__ int lcnt[NB];
    __shared__ int lbase[NB];
    const long long idx = (long long)idx_p[0];
    const int*   rows = adj_rows + idx * (long long)N_EDGES;
    const int*   cols = adj_cols + idx * (long long)N_EDGES;
    const float* vals = adj_vals + idx * (long long)N_EDGES;

    const int tile = blockIdx.x * P3_TILE;
    for (int i = threadIdx.x; i < NB; i += P3_THREADS) lcnt[i] = 0;
    __syncthreads();

    int rc[P3_EPT];                       // cached row (or -1)
#pragma unroll
    for (int k = 0; k < P3_EPT; ++k) {
        const int e = tile + k * P3_THREADS + (int)threadIdx.x;
        rc[k] = (e < N_EDGES) ? rows[e] : -1;
        if (rc[k] >= 0) atomicAdd(&lcnt[rc[k] >> 7], 1);
    }
    __syncthreads();

    for (int i = threadIdx.x; i < NB; i += P3_THREADS) {
        const int c = lcnt[i];
        lbase[i] = c ? atomicAdd(&bcursor[i], c) : 0;
        lcnt[i]  = 0;
    }
    __syncthreads();

#pragma unroll
    for (int k = 0; k < P3_EPT; ++k) {
        const int r = rc[k];
        if (r >= 0) {
            const int e = tile + k * P3_THREADS + (int)threadIdx.x;
            const int b = r >> 7;
            const int pos = lbase[b] + atomicAdd(&lcnt[b], 1);
            pairs[pos] = make_int2(((r & (RPB - 1)) << 24) | cols[e],
                                   __float_as_int(vals[e]));
        }
    }
}

// P3 (fused sort+spmm): per-bucket 2-level LDS counting sort + SpMM.
// PRE=1: cell counts precomputed in global cellhist (no Pass A).
template <bool PRE>
__global__ __launch_bounds__(1024) void sort_spmm_kernel(
    const uint4* __restrict__ xb, const int* __restrict__ bptr,
    const int2* __restrict__ pairs, const int* __restrict__ cellhist,
    float* __restrict__ out)
{
    __shared__ int2 staged[CAP];          // 36,864 B, sorted by (row, colslice)
    __shared__ int  cellptr[NCELL];       // 12,800 B: cursors
    __shared__ int  rs[RPB + 1];          //    516 B: per-row start
    __shared__ int  scan[1024];           //  4,096 B
    const int b    = blockIdx.x;
    const int t    = (int)threadIdx.x;
    const int base = bptr[b];
    const int n    = bptr[b + 1] - base;

    const int i0 = t * 4;
    int v0 = 0, v1 = 0, v2 = 0, v3 = 0;

    if constexpr (PRE) {
        const int* cb = cellhist + (size_t)b * NCELL;
        if (i0 + 0 < NCELL) v0 = cb[i0 + 0];
        if (i0 + 1 < NCELL) v1 = cb[i0 + 1];
        if (i0 + 2 < NCELL) v2 = cb[i0 + 2];
        if (i0 + 3 < NCELL) v3 = cb[i0 + 3];
    } else {
        for (int i = t; i < NCELL; i += 1024) cellptr[i] = 0;
        __syncthreads();
        for (int i = t; i < n; i += 1024) {
            const int2 p = pairs[base + i];
            const int row = ((unsigned)p.x) >> 24;
            const int col = p.x & 0xFFFFFF;
            atomicAdd(&cellptr[row * NS + (col >> 12)], 1);
        }
        __syncthreads();
        if (i0 + 0 < NCELL) v0 = cellptr[i0 + 0];
        if (i0 + 1 < NCELL) v1 = cellptr[i0 + 1];
        if (i0 + 2 < NCELL) v2 = cellptr[i0 + 2];
        if (i0 + 3 < NCELL) v3 = cellptr[i0 + 3];
        __syncthreads();
    }

    // Exclusive scan over NCELL cells: thread t owns cells [4t, 4t+4).
    const int s = v0 + v1 + v2 + v3;
    scan[t] = s;
    __syncthreads();
    for (int off = 1; off < 1024; off <<= 1) {
        int u = (t >= off) ? scan[t - off] : 0;
        __syncthreads();
        scan[t] += u;
        __syncthreads();
    }
    int run = scan[t] - s;                // exclusive prefix for cell i0
    if (i0 + 0 < NCELL) { cellptr[i0 + 0] = run; run += v0; }
    if (i0 + 1 < NCELL) { cellptr[i0 + 1] = run; run += v1; }
    if (i0 + 2 < NCELL) { cellptr[i0 + 2] = run; run += v2; }
    if (i0 + 3 < NCELL) { cellptr[i0 + 3] = run; run += v3; }
    __syncthreads();

    // Row starts (before cellptr mutates into cursors).
    if (t < RPB) rs[t] = cellptr[t * NS];
    if (t == 0)  rs[RPB] = n;
    __syncthreads();

    // Scatter into LDS sorted by (row, colslice).
    for (int i = t; i < n; i += 1024) {
        const int2 p = pairs[base + i];
        const int row = ((unsigned)p.x) >> 24;
        const int col = p.x & 0xFFFFFF;
        const int pos = atomicAdd(&cellptr[row * NS + (col >> 12)], 1);
        if (pos < CAP) staged[pos] = p;
    }
    __syncthreads();

    // SpMM: group g of wave w handles rows (w*4+g) + 64*k, k=0,1.
    const int w    = t >> 6;
    const int lane = t & 63;
    const int g    = lane >> 4;          // group within wave
    const int sl   = lane & 15;          // 8-feature slot
    const int grp  = w * 4 + g;          // 0..63

    for (int k = 0; k < 2; ++k) {
        const int r   = grp + 64 * k;    // 0..127
        const int row = b * RPB + r;
        if (row >= N_NODES) break;
        const int s0 = rs[r];
        const int e0 = rs[r + 1];

        float4 a0 = make_float4(0.f, 0.f, 0.f, 0.f);
        float4 a1 = make_float4(0.f, 0.f, 0.f, 0.f);
        for (int j = s0; j < e0; ++j) {
            const int2  p   = staged[j];          // same-addr LDS broadcast
            const int   col = p.x & 0xFFFFFF;
            const float vj  = __int_as_float(p.y);
            const uint4 wv  = xb[(size_t)col * (D_FEAT / 8) + sl];
            a0.x += vj * __uint_as_float(wv.x << 16);
            a0.y += vj * __uint_as_float(wv.x & 0xffff0000u);
            a0.z += vj * __uint_as_float(wv.y << 16);
            a0.w += vj * __uint_as_float(wv.y & 0xffff0000u);
            a1.x += vj * __uint_as_float(wv.z << 16);
            a1.y += vj * __uint_as_float(wv.z & 0xffff0000u);
            a1.z += vj * __uint_as_float(wv.w << 16);
            a1.w += vj * __uint_as_float(wv.w & 0xffff0000u);
        }
        float* op = out + (size_t)row * D_FEAT + sl * 8;
        *reinterpret_cast<float4*>(op)     = a0;
        *reinterpret_cast<float4*>(op + 4) = a1;
    }
}

// Fallback (tiny workspace): edge-parallel atomic kernel.
__global__ __launch_bounds__(256) void spmm_atomic_kernel(
    const float* __restrict__ x,
    const int*   __restrict__ adj_rows,
    const int*   __restrict__ adj_cols,
    const float* __restrict__ adj_vals,
    const int*   __restrict__ idx_p,
    float*       __restrict__ out)
{
    const long long idx = (long long)idx_p[0];
    const int*   rows = adj_rows + idx * (long long)N_EDGES;
    const int*   cols = adj_cols + idx * (long long)N_EDGES;
    const float* vals = adj_vals + idx * (long long)N_EDGES;

    long long tt = (long long)blockIdx.x * blockDim.x + threadIdx.x;
    long long e  = tt >> 5;
    int       f4 = (int)(tt & 31);
    if (e >= N_EDGES) return;

    const int   r = rows[e];
    const int   c = cols[e];
    const float v = vals[e];
    const float4 xv =
        *reinterpret_cast<const float4*>(x + (long long)c * D_FEAT + f4 * 4);
    float* o = out + (long long)r * D_FEAT + f4 * 4;
    unsafeAtomicAdd(o + 0, v * xv.x);
    unsafeAtomicAdd(o + 1, v * xv.y);
    unsafeAtomicAdd(o + 2, v * xv.z);
    unsafeAtomicAdd(o + 3, v * xv.w);
}

extern "C" void kernel_launch(void* const* d_in, const int* in_sizes, int n_in,
                              void* d_out, int out_size, void* d_ws, size_t ws_size,
                              hipStream_t stream) {
    const float* x        = (const float*)d_in[0];
    const int*   adj_rows = (const int*)  d_in[1];
    const int*   adj_cols = (const int*)  d_in[2];
    const float* adj_vals = (const float*)d_in[3];
    const int*   idx_p    = (const int*)  d_in[4];
    float*       out      = (float*)d_out;

    // Workspace layout (4-byte elements):
    //   bhist    : NB
    //   bptr     : NB+1
    //   bcursor  : NB
    //   pad      : to multiple-of-4 ints
    //   [PRE only] cellhist : NCELLG (10 MB)
    //   pairs    : N_EDGES int2            (25.6 MB)
    //   xb       : N_NODES*D_FEAT bf16     (25.6 MB)
    const size_t n_meta_raw = (size_t)NB * 3 + 1;
    const size_t n_meta     = (n_meta_raw + 3) & ~(size_t)3;
    const size_t xb_bytes   = (size_t)N_NODES * D_FEAT * 2;
    const size_t need_pre   = (n_meta + NCELLG + (size_t)2 * N_EDGES) * 4 + xb_bytes;
    const size_t need_base  = (n_meta + (size_t)2 * N_EDGES) * 4 + xb_bytes;

    if (ws_size < need_base) {
        hipMemsetAsync(out, 0, (size_t)out_size * sizeof(float), stream);
        const long long total_threads = (long long)N_EDGES * 32;
        const int block = 256;
        const long long grid = (total_threads + block - 1) / block;
        spmm_atomic_kernel<<<(dim3)(unsigned)grid, block, 0, stream>>>(
            x, adj_rows, adj_cols, adj_vals, idx_p, out);
        return;
    }

    const bool pre = (ws_size >= need_pre);

    int*   bhist    = (int*)d_ws;
    int*   bptr     = bhist + NB;
    int*   bcursor  = bptr + (NB + 1);
    int*   cellhist = pre ? ((int*)d_ws + n_meta) : nullptr;
    int*   after    = (int*)d_ws + n_meta + (pre ? NCELLG : 0);
    int2*  pairs    = (int2*)after;
    uint4* xb       = (uint4*)(after + (size_t)2 * N_EDGES);

    // Zero bhist (+ cellhist when present) in one async memset.
    hipMemsetAsync(d_ws, 0,
                   (n_meta + (pre ? NCELLG : 0)) * sizeof(int), stream);

    cvt_bhist_kernel<<<CVT_BLOCKS + HIST_BLOCKS, 256, 0, stream>>>(
        x, xb, adj_rows, adj_cols, idx_p, bhist, cellhist);
    bscan_kernel<<<1, 1024, 0, stream>>>(bhist, bptr, bcursor);
    partition_kernel<<<P3_GRID, P3_THREADS, 0, stream>>>(
        adj_rows, adj_cols, adj_vals, idx_p, bcursor, pairs);
    if (pre)
        sort_spmm_kernel<true><<<NB, 1024, 0, stream>>>(
            xb, bptr, pairs, cellhist, out);
    else
        sort_spmm_kernel<false><<<NB, 1024, 0, stream>>>(
            xb, bptr, pairs, nullptr, out);
}

// Round 11
// 222.786 us; speedup vs baseline: 1.5488x; 1.5488x over previous
//
#include <hip/hip_runtime.h>

#define N_NODES 100000
#define N_EDGES 3200000
#define D_FEAT  128

#define RPB 128                              // rows per bucket (row >> 7)
#define NB ((N_NODES + RPB - 1) / RPB)       // 782 buckets
#define P3_THREADS 512
#define P3_EPT 32                            // edges per thread in partition
#define P3_TILE (P3_THREADS * P3_EPT)        // 16384 edges per partition block
#define P3_GRID ((N_EDGES + P3_TILE - 1) / P3_TILE)   // 196

#define NS 25                                // col slices (col >> 12, 1MB bf16 each)
#define NCELL (RPB * NS)                     // 3200 sort cells
#define CAP 4608                             // LDS staging cap (bucket max ~4330)

#define CVT_BLOCKS 2048
#define HIST_BLOCKS 256

// ---------------------------------------------------------------------------
// Pipeline (R11 = R9 + partition tuning; R10's global cellhist REVERTED —
// 3.2M random global atomics over 10MB were ~25 G atomics/s of miss RMW).
//   0) cvt_bhist (FUSED): blocks [0,2048) convert x -> packed bf16;
//      blocks [2048,2304) build the 128-row bucket histogram (LDS).
//   1) bscan: exclusive scan of NB bucket counts.
//   2) partition: counting-partition into 128-row buckets. 16384 edges/block
//      -> ~21-edge contiguous runs per bucket (write amp ~1.25x); rows
//      reg-cached across count/place phases (no re-read).
//   3) sort_spmm: one 1024-thr block per bucket. In-LDS counting sort with
//      2-level key (row_lo, col>>12) -> each row's edges in ascending
//      col-slice order; resident blocks sweep x together -> ~53% L2 hit.
//      SpMM: 16-lane group per row, LDS same-addr broadcast of (col,val),
//      f32 register accumulation, one 512B coalesced row write.
// R5-R10 lesson: sort_spmm pins the ~5.6 TB/s TCC request ceiling for
// random 256B gathers (819MB requests / 147us); bytes-levers are exhausted
// (fp8 breaks the 0.38 error budget). Only preprocessing overhead remains.
// ---------------------------------------------------------------------------

__device__ inline unsigned bf16rne(float f) {
    unsigned u = __float_as_uint(f);
    u += 0x7fffu + ((u >> 16) & 1u);
    return u >> 16;
}
__device__ inline unsigned pack2(float lo, float hi) {
    return bf16rne(lo) | (bf16rne(hi) << 16);
}

// P0: fused x->bf16 convert (blocks < CVT_BLOCKS) + bucket histogram (rest).
__global__ __launch_bounds__(256) void cvt_bhist_kernel(
    const float* __restrict__ x, uint4* __restrict__ xb,
    const int* __restrict__ adj_rows, const int* __restrict__ idx_p,
    int* __restrict__ bhist)
{
    __shared__ int lh[NB];
    if (blockIdx.x < CVT_BLOCKS) {
        const int total = N_NODES * D_FEAT / 8;
        for (int i = blockIdx.x * 256 + threadIdx.x; i < total;
             i += CVT_BLOCKS * 256) {
            const float4 a = reinterpret_cast<const float4*>(x)[2 * i];
            const float4 b = reinterpret_cast<const float4*>(x)[2 * i + 1];
            uint4 o;
            o.x = pack2(a.x, a.y);
            o.y = pack2(a.z, a.w);
            o.z = pack2(b.x, b.y);
            o.w = pack2(b.z, b.w);
            xb[i] = o;
        }
    } else {
        for (int i = threadIdx.x; i < NB; i += 256) lh[i] = 0;
        __syncthreads();
        const long long idx = (long long)idx_p[0];
        const int* rows = adj_rows + idx * (long long)N_EDGES;
        for (int e = (blockIdx.x - CVT_BLOCKS) * 256 + threadIdx.x;
             e < N_EDGES; e += HIST_BLOCKS * 256)
            atomicAdd(&lh[rows[e] >> 7], 1);
        __syncthreads();
        for (int i = threadIdx.x; i < NB; i += 256)
            if (lh[i]) atomicAdd(&bhist[i], lh[i]);
    }
}

// P1: exclusive scan of NB bucket counts (single block), init cursors.
__global__ __launch_bounds__(1024) void bscan_kernel(
    const int* __restrict__ bhist, int* __restrict__ bptr,
    int* __restrict__ bcursor)
{
    __shared__ int lds[1024];
    const int t = threadIdx.x;
    const int v = (t < NB) ? bhist[t] : 0;
    lds[t] = v;
    __syncthreads();
    for (int off = 1; off < 1024; off <<= 1) {
        int u = (t >= off) ? lds[t - off] : 0;
        __syncthreads();
        lds[t] += u;
        __syncthreads();
    }
    if (t < NB) {
        const int excl = lds[t] - v;
        bptr[t]    = excl;
        bcursor[t] = excl;
    }
    if (t == NB - 1) bptr[NB] = lds[t];
}

// P2: partition edges into buckets; rows reg-cached across phases.
__global__ __launch_bounds__(P3_THREADS) void partition_kernel(
    const int* __restrict__ adj_rows, const int* __restrict__ adj_cols,
    const float* __restrict__ adj_vals, const int* __restrict__ idx_p,
    int* __restrict__ bcursor, int2* __restrict__ pairs)
{
    __shared__ int lcnt[NB];
    __shared__ int lbase[NB];
    const long long idx = (long long)idx_p[0];
    const int*   rows = adj_rows + idx * (long long)N_EDGES;
    const int*   cols = adj_cols + idx * (long long)N_EDGES;
    const float* vals = adj_vals + idx * (long long)N_EDGES;

    const int tile = blockIdx.x * P3_TILE;
    for (int i = threadIdx.x; i < NB; i += P3_THREADS) lcnt[i] = 0;
    __syncthreads();

    int rc[P3_EPT];                       // cached row (or -1)
#pragma unroll
    for (int k = 0; k < P3_EPT; ++k) {
        const int e = tile + k * P3_THREADS + (int)threadIdx.x;
        rc[k] = (e < N_EDGES) ? rows[e] : -1;
        if (rc[k] >= 0) atomicAdd(&lcnt[rc[k] >> 7], 1);
    }
    __syncthreads();

    for (int i = threadIdx.x; i < NB; i += P3_THREADS) {
        const int c = lcnt[i];
        lbase[i] = c ? atomicAdd(&bcursor[i], c) : 0;
        lcnt[i]  = 0;
    }
    __syncthreads();

#pragma unroll
    for (int k = 0; k < P3_EPT; ++k) {
        const int r = rc[k];
        if (r >= 0) {
            const int e = tile + k * P3_THREADS + (int)threadIdx.x;
            const int b = r >> 7;
            const int pos = lbase[b] + atomicAdd(&lcnt[b], 1);
            pairs[pos] = make_int2(((r & (RPB - 1)) << 24) | cols[e],
                                   __float_as_int(vals[e]));
        }
    }
}

// P3 (fused sort+spmm): per-bucket 2-level LDS counting sort + SpMM.
__global__ __launch_bounds__(1024) void sort_spmm_kernel(
    const uint4* __restrict__ xb, const int* __restrict__ bptr,
    const int2* __restrict__ pairs, float* __restrict__ out)
{
    __shared__ int2 staged[CAP];          // 36,864 B, sorted by (row, colslice)
    __shared__ int  cellptr[NCELL];       // 12,800 B: counts -> scan -> cursors
    __shared__ int  rs[RPB + 1];          //    516 B: per-row start
    __shared__ int  scan[1024];           //  4,096 B
    const int b    = blockIdx.x;
    const int t    = (int)threadIdx.x;
    const int base = bptr[b];
    const int n    = bptr[b + 1] - base;

    for (int i = t; i < NCELL; i += 1024) cellptr[i] = 0;
    __syncthreads();

    // Pass A: count cells (key = row_lo * NS + col_slice).
    for (int i = t; i < n; i += 1024) {
        const int2 p = pairs[base + i];
        const int row = ((unsigned)p.x) >> 24;
        const int col = p.x & 0xFFFFFF;
        atomicAdd(&cellptr[row * NS + (col >> 12)], 1);
    }
    __syncthreads();

    // Exclusive scan over NCELL cells: thread t owns cells [4t, 4t+4).
    const int i0 = t * 4;
    int v0 = 0, v1 = 0, v2 = 0, v3 = 0;
    if (i0 + 0 < NCELL) v0 = cellptr[i0 + 0];
    if (i0 + 1 < NCELL) v1 = cellptr[i0 + 1];
    if (i0 + 2 < NCELL) v2 = cellptr[i0 + 2];
    if (i0 + 3 < NCELL) v3 = cellptr[i0 + 3];
    const int s = v0 + v1 + v2 + v3;
    scan[t] = s;
    __syncthreads();
    for (int off = 1; off < 1024; off <<= 1) {
        int u = (t >= off) ? scan[t - off] : 0;
        __syncthreads();
        scan[t] += u;
        __syncthreads();
    }
    int run = scan[t] - s;                // exclusive prefix for cell i0
    if (i0 + 0 < NCELL) { cellptr[i0 + 0] = run; run += v0; }
    if (i0 + 1 < NCELL) { cellptr[i0 + 1] = run; run += v1; }
    if (i0 + 2 < NCELL) { cellptr[i0 + 2] = run; run += v2; }
    if (i0 + 3 < NCELL) { cellptr[i0 + 3] = run; run += v3; }
    __syncthreads();

    // Row starts (before cellptr mutates into cursors).
    if (t < RPB) rs[t] = cellptr[t * NS];
    if (t == 0)  rs[RPB] = n;
    __syncthreads();

    // Pass B: scatter into LDS sorted by (row, colslice).
    for (int i = t; i < n; i += 1024) {
        const int2 p = pairs[base + i];
        const int row = ((unsigned)p.x) >> 24;
        const int col = p.x & 0xFFFFFF;
        const int pos = atomicAdd(&cellptr[row * NS + (col >> 12)], 1);
        if (pos < CAP) staged[pos] = p;
    }
    __syncthreads();

    // SpMM: group g of wave w handles rows (w*4+g) + 64*k, k=0,1.
    const int w    = t >> 6;
    const int lane = t & 63;
    const int g    = lane >> 4;          // group within wave
    const int sl   = lane & 15;          // 8-feature slot
    const int grp  = w * 4 + g;          // 0..63

    for (int k = 0; k < 2; ++k) {
        const int r   = grp + 64 * k;    // 0..127
        const int row = b * RPB + r;
        if (row >= N_NODES) break;
        const int s0 = rs[r];
        const int e0 = rs[r + 1];

        float4 a0 = make_float4(0.f, 0.f, 0.f, 0.f);
        float4 a1 = make_float4(0.f, 0.f, 0.f, 0.f);
        for (int j = s0; j < e0; ++j) {
            const int2  p   = staged[j];          // same-addr LDS broadcast
            const int   col = p.x & 0xFFFFFF;
            const float vj  = __int_as_float(p.y);
            const uint4 wv  = xb[(size_t)col * (D_FEAT / 8) + sl];
            a0.x += vj * __uint_as_float(wv.x << 16);
            a0.y += vj * __uint_as_float(wv.x & 0xffff0000u);
            a0.z += vj * __uint_as_float(wv.y << 16);
            a0.w += vj * __uint_as_float(wv.y & 0xffff0000u);
            a1.x += vj * __uint_as_float(wv.z << 16);
            a1.y += vj * __uint_as_float(wv.z & 0xffff0000u);
            a1.z += vj * __uint_as_float(wv.w << 16);
            a1.w += vj * __uint_as_float(wv.w & 0xffff0000u);
        }
        float* op = out + (size_t)row * D_FEAT + sl * 8;
        *reinterpret_cast<float4*>(op)     = a0;
        *reinterpret_cast<float4*>(op + 4) = a1;
    }
}

// Fallback (tiny workspace): edge-parallel atomic kernel.
__global__ __launch_bounds__(256) void spmm_atomic_kernel(
    const float* __restrict__ x,
    const int*   __restrict__ adj_rows,
    const int*   __restrict__ adj_cols,
    const float* __restrict__ adj_vals,
    const int*   __restrict__ idx_p,
    float*       __restrict__ out)
{
    const long long idx = (long long)idx_p[0];
    const int*   rows = adj_rows + idx * (long long)N_EDGES;
    const int*   cols = adj_cols + idx * (long long)N_EDGES;
    const float* vals = adj_vals + idx * (long long)N_EDGES;

    long long tt = (long long)blockIdx.x * blockDim.x + threadIdx.x;
    long long e  = tt >> 5;
    int       f4 = (int)(tt & 31);
    if (e >= N_EDGES) return;

    const int   r = rows[e];
    const int   c = cols[e];
    const float v = vals[e];
    const float4 xv =
        *reinterpret_cast<const float4*>(x + (long long)c * D_FEAT + f4 * 4);
    float* o = out + (long long)r * D_FEAT + f4 * 4;
    unsafeAtomicAdd(o + 0, v * xv.x);
    unsafeAtomicAdd(o + 1, v * xv.y);
    unsafeAtomicAdd(o + 2, v * xv.z);
    unsafeAtomicAdd(o + 3, v * xv.w);
}

extern "C" void kernel_launch(void* const* d_in, const int* in_sizes, int n_in,
                              void* d_out, int out_size, void* d_ws, size_t ws_size,
                              hipStream_t stream) {
    const float* x        = (const float*)d_in[0];
    const int*   adj_rows = (const int*)  d_in[1];
    const int*   adj_cols = (const int*)  d_in[2];
    const float* adj_vals = (const float*)d_in[3];
    const int*   idx_p    = (const int*)  d_in[4];
    float*       out      = (float*)d_out;

    // Workspace layout (4-byte elements):
    //   bhist   : NB
    //   bptr    : NB+1
    //   bcursor : NB
    //   pad     : to multiple-of-4 ints (16B-align pairs & xb)
    //   pairs   : N_EDGES int2              (25.6 MB)
    //   xb      : N_NODES*D_FEAT bf16       (25.6 MB)
    const size_t n_meta_raw = (size_t)NB * 3 + 1;
    const size_t n_meta     = (n_meta_raw + 3) & ~(size_t)3;
    const size_t need       = (n_meta + (size_t)2 * N_EDGES) * 4
                            + (size_t)N_NODES * D_FEAT * 2;

    if (ws_size < need) {
        hipMemsetAsync(out, 0, (size_t)out_size * sizeof(float), stream);
        const long long total_threads = (long long)N_EDGES * 32;
        const int block = 256;
        const long long grid = (total_threads + block - 1) / block;
        spmm_atomic_kernel<<<(dim3)(unsigned)grid, block, 0, stream>>>(
            x, adj_rows, adj_cols, adj_vals, idx_p, out);
        return;
    }

    int*   bhist   = (int*)d_ws;
    int*   bptr    = bhist + NB;
    int*   bcursor = bptr + (NB + 1);
    int2*  pairs   = (int2*)((int*)d_ws + n_meta);
    uint4* xb      = (uint4*)((int*)d_ws + n_meta + (size_t)2 * N_EDGES);

    hipMemsetAsync(bhist, 0, (size_t)NB * sizeof(int), stream);

    cvt_bhist_kernel<<<CVT_BLOCKS + HIST_BLOCKS, 256, 0, stream>>>(
        x, xb, adj_rows, idx_p, bhist);
    bscan_kernel<<<1, 1024, 0, stream>>>(bhist, bptr, bcursor);
    partition_kernel<<<P3_GRID, P3_THREADS, 0, stream>>>(
        adj_rows, adj_cols, adj_vals, idx_p, bcursor, pairs);
    sort_spmm_kernel<<<NB, 1024, 0, stream>>>(xb, bptr, pairs, out);
}

// Round 12
// 220.977 us; speedup vs baseline: 1.5615x; 1.0082x over previous
//
#include <hip/hip_runtime.h>

#define N_NODES 100000
#define N_EDGES 3200000
#define D_FEAT  128

#define RPB 128                              // rows per bucket (row >> 7)
#define NB ((N_NODES + RPB - 1) / RPB)       // 782 buckets
#define P3_THREADS 512
#define P3_EPT 32                            // edges per thread in partition
#define P3_TILE (P3_THREADS * P3_EPT)        // 16384 edges per partition block
#define P3_GRID ((N_EDGES + P3_TILE - 1) / P3_TILE)   // 196

#define NS 25                                // col slices (col >> 12, 1MB bf16 each)
#define NCELL (RPB * NS)                     // 3200 sort cells
#define CAP 4608                             // LDS staging cap (bucket max ~4330)

#define HIST_BLOCKS 768                      // hist blocks FIRST (start in wave 1)
#define CVT_BLOCKS 1536

typedef int   nt_i2 __attribute__((ext_vector_type(2)));
typedef float nt_f4 __attribute__((ext_vector_type(4)));

// ---------------------------------------------------------------------------
// Pipeline (R12 = R11 + overhead cuts; core gather untouched — it pins the
// ~5.6 TB/s random-256B request ceiling, R5-R11).
//   0) cvt_bhist: blocks [0,768) bucket histogram (16 iters each);
//      blocks [768,2304) x -> packed bf16.
//   1) partition: each block re-derives the bucket scan locally from bhist
//      (replaces the bscan kernel); bcursor is a relative counter; block 0
//      publishes bptr. Rows reg-cached across count/place phases.
//   2) sort_spmm: per-bucket 2-level (row, col>>12) LDS counting sort +
//      SpMM (16-lane group per row, LDS same-addr broadcast, f32 reg accum).
//      Pass-B pair loads and out-row stores are NONTEMPORAL to keep x
//      slices resident in L2 during the gather phase.
// ---------------------------------------------------------------------------

__device__ inline unsigned bf16rne(float f) {
    unsigned u = __float_as_uint(f);
    u += 0x7fffu + ((u >> 16) & 1u);
    return u >> 16;
}
__device__ inline unsigned pack2(float lo, float hi) {
    return bf16rne(lo) | (bf16rne(hi) << 16);
}

// P0: fused bucket histogram (blocks < HIST_BLOCKS) + x->bf16 convert (rest).
__global__ __launch_bounds__(256) void cvt_bhist_kernel(
    const float* __restrict__ x, uint4* __restrict__ xb,
    const int* __restrict__ adj_rows, const int* __restrict__ idx_p,
    int* __restrict__ bhist)
{
    __shared__ int lh[NB];
    if (blockIdx.x < HIST_BLOCKS) {
        for (int i = threadIdx.x; i < NB; i += 256) lh[i] = 0;
        __syncthreads();
        const long long idx = (long long)idx_p[0];
        const int* rows = adj_rows + idx * (long long)N_EDGES;
        for (int e = blockIdx.x * 256 + threadIdx.x; e < N_EDGES;
             e += HIST_BLOCKS * 256)
            atomicAdd(&lh[rows[e] >> 7], 1);
        __syncthreads();
        for (int i = threadIdx.x; i < NB; i += 256)
            if (lh[i]) atomicAdd(&bhist[i], lh[i]);
    } else {
        const int total = N_NODES * D_FEAT / 8;
        for (int i = (blockIdx.x - HIST_BLOCKS) * 256 + threadIdx.x; i < total;
             i += CVT_BLOCKS * 256) {
            const float4 a = reinterpret_cast<const float4*>(x)[2 * i];
            const float4 b = reinterpret_cast<const float4*>(x)[2 * i + 1];
            uint4 o;
            o.x = pack2(a.x, a.y);
            o.y = pack2(a.z, a.w);
            o.z = pack2(b.x, b.y);
            o.w = pack2(b.z, b.w);
            xb[i] = o;
        }
    }
}

// P1: partition edges into buckets. Each block locally scans bhist -> lbptr
// (absolute bucket starts); bcursor holds RELATIVE reservations (memset 0).
// Block 0 publishes bptr for sort_spmm. Rows reg-cached across phases.
__global__ __launch_bounds__(P3_THREADS) void partition_kernel(
    const int* __restrict__ adj_rows, const int* __restrict__ adj_cols,
    const float* __restrict__ adj_vals, const int* __restrict__ idx_p,
    const int* __restrict__ bhist, int* __restrict__ bcursor,
    int* __restrict__ bptr, int2* __restrict__ pairs)
{
    __shared__ int lcnt[NB];
    __shared__ int lbase[NB];
    __shared__ int lbptr[NB];
    __shared__ int sscan[P3_THREADS];
    const int t = (int)threadIdx.x;

    // Local exclusive scan of bhist: thread t owns elements 2t, 2t+1.
    const int e0 = 2 * t, e1 = 2 * t + 1;
    const int v0 = (e0 < NB) ? bhist[e0] : 0;
    const int v1 = (e1 < NB) ? bhist[e1] : 0;
    const int ss = v0 + v1;
    sscan[t] = ss;
    if (t < NB) lcnt[t] = 0;
    if (t + P3_THREADS < NB) lcnt[t + P3_THREADS] = 0;
    __syncthreads();
    for (int off = 1; off < P3_THREADS; off <<= 1) {
        int u = (t >= off) ? sscan[t - off] : 0;
        __syncthreads();
        sscan[t] += u;
        __syncthreads();
    }
    const int pre = sscan[t] - ss;        // exclusive prefix of element 2t
    if (e0 < NB) lbptr[e0] = pre;
    if (e1 < NB) lbptr[e1] = pre + v0;
    if (blockIdx.x == 0) {
        if (e0 < NB) bptr[e0] = pre;
        if (e1 < NB) bptr[e1] = pre + v0;
        if (t == P3_THREADS - 1) bptr[NB] = sscan[t];
    }
    __syncthreads();

    const long long idx = (long long)idx_p[0];
    const int*   rows = adj_rows + idx * (long long)N_EDGES;
    const int*   cols = adj_cols + idx * (long long)N_EDGES;
    const float* vals = adj_vals + idx * (long long)N_EDGES;
    const int tile = blockIdx.x * P3_TILE;

    int rc[P3_EPT];                       // cached row (or -1)
#pragma unroll
    for (int k = 0; k < P3_EPT; ++k) {
        const int e = tile + k * P3_THREADS + t;
        rc[k] = (e < N_EDGES) ? rows[e] : -1;
        if (rc[k] >= 0) atomicAdd(&lcnt[rc[k] >> 7], 1);
    }
    __syncthreads();

    for (int i = t; i < NB; i += P3_THREADS) {
        const int c = lcnt[i];
        lbase[i] = c ? atomicAdd(&bcursor[i], c) : 0;   // relative
        lcnt[i]  = 0;
    }
    __syncthreads();

#pragma unroll
    for (int k = 0; k < P3_EPT; ++k) {
        const int r = rc[k];
        if (r >= 0) {
            const int e = tile + k * P3_THREADS + t;
            const int b = r >> 7;
            const int pos = lbptr[b] + lbase[b] + atomicAdd(&lcnt[b], 1);
            pairs[pos] = make_int2(((r & (RPB - 1)) << 24) | cols[e],
                                   __float_as_int(vals[e]));
        }
    }
}

// P2 (fused sort+spmm): per-bucket 2-level LDS counting sort + SpMM.
__global__ __launch_bounds__(1024) void sort_spmm_kernel(
    const uint4* __restrict__ xb, const int* __restrict__ bptr,
    const int2* __restrict__ pairs, float* __restrict__ out)
{
    __shared__ int2 staged[CAP];          // 36,864 B, sorted by (row, colslice)
    __shared__ int  cellptr[NCELL];       // 12,800 B: counts -> scan -> cursors
    __shared__ int  rs[RPB + 1];          //    516 B: per-row start
    __shared__ int  scan[1024];           //  4,096 B
    const int b    = blockIdx.x;
    const int t    = (int)threadIdx.x;
    const int base = bptr[b];
    const int n    = bptr[b + 1] - base;

    for (int i = t; i < NCELL; i += 1024) cellptr[i] = 0;
    __syncthreads();

    // Pass A: count cells (key = row_lo * NS + col_slice).
    for (int i = t; i < n; i += 1024) {
        const int2 p = pairs[base + i];
        const int row = ((unsigned)p.x) >> 24;
        const int col = p.x & 0xFFFFFF;
        atomicAdd(&cellptr[row * NS + (col >> 12)], 1);
    }
    __syncthreads();

    // Exclusive scan over NCELL cells: thread t owns cells [4t, 4t+4).
    const int i0 = t * 4;
    int v0 = 0, v1 = 0, v2 = 0, v3 = 0;
    if (i0 + 0 < NCELL) v0 = cellptr[i0 + 0];
    if (i0 + 1 < NCELL) v1 = cellptr[i0 + 1];
    if (i0 + 2 < NCELL) v2 = cellptr[i0 + 2];
    if (i0 + 3 < NCELL) v3 = cellptr[i0 + 3];
    const int s = v0 + v1 + v2 + v3;
    scan[t] = s;
    __syncthreads();
    for (int off = 1; off < 1024; off <<= 1) {
        int u = (t >= off) ? scan[t - off] : 0;
        __syncthreads();
        scan[t] += u;
        __syncthreads();
    }
    int run = scan[t] - s;                // exclusive prefix for cell i0
    if (i0 + 0 < NCELL) { cellptr[i0 + 0] = run; run += v0; }
    if (i0 + 1 < NCELL) { cellptr[i0 + 1] = run; run += v1; }
    if (i0 + 2 < NCELL) { cellptr[i0 + 2] = run; run += v2; }
    if (i0 + 3 < NCELL) { cellptr[i0 + 3] = run; run += v3; }
    __syncthreads();

    // Row starts (before cellptr mutates into cursors).
    if (t < RPB) rs[t] = cellptr[t * NS];
    if (t == 0)  rs[RPB] = n;
    __syncthreads();

    // Pass B: scatter into LDS sorted by (row, colslice). NT load (last use).
    for (int i = t; i < n; i += 1024) {
        const nt_i2 pr = __builtin_nontemporal_load(
            reinterpret_cast<const nt_i2*>(pairs + base + i));
        const int w0 = pr[0];
        const int row = ((unsigned)w0) >> 24;
        const int col = w0 & 0xFFFFFF;
        const int pos = atomicAdd(&cellptr[row * NS + (col >> 12)], 1);
        if (pos < CAP) staged[pos] = make_int2(w0, pr[1]);
    }
    __syncthreads();

    // SpMM: group g of wave w handles rows (w*4+g) + 64*k, k=0,1.
    const int w    = t >> 6;
    const int lane = t & 63;
    const int g    = lane >> 4;          // group within wave
    const int sl   = lane & 15;          // 8-feature slot
    const int grp  = w * 4 + g;          // 0..63

    for (int k = 0; k < 2; ++k) {
        const int r   = grp + 64 * k;    // 0..127
        const int row = b * RPB + r;
        if (row >= N_NODES) break;
        const int s0 = rs[r];
        const int e0 = rs[r + 1];

        float4 a0 = make_float4(0.f, 0.f, 0.f, 0.f);
        float4 a1 = make_float4(0.f, 0.f, 0.f, 0.f);
        for (int j = s0; j < e0; ++j) {
            const int2  p   = staged[j];          // same-addr LDS broadcast
            const int   col = p.x & 0xFFFFFF;
            const float vj  = __int_as_float(p.y);
            const uint4 wv  = xb[(size_t)col * (D_FEAT / 8) + sl];
            a0.x += vj * __uint_as_float(wv.x << 16);
            a0.y += vj * __uint_as_float(wv.x & 0xffff0000u);
            a0.z += vj * __uint_as_float(wv.y << 16);
            a0.w += vj * __uint_as_float(wv.y & 0xffff0000u);
            a1.x += vj * __uint_as_float(wv.z << 16);
            a1.y += vj * __uint_as_float(wv.z & 0xffff0000u);
            a1.z += vj * __uint_as_float(wv.w << 16);
            a1.w += vj * __uint_as_float(wv.w & 0xffff0000u);
        }
        float* op = out + (size_t)row * D_FEAT + sl * 8;
        nt_f4 o0 = {a0.x, a0.y, a0.z, a0.w};
        nt_f4 o1 = {a1.x, a1.y, a1.z, a1.w};
        __builtin_nontemporal_store(o0, reinterpret_cast<nt_f4*>(op));
        __builtin_nontemporal_store(o1, reinterpret_cast<nt_f4*>(op) + 1);
    }
}

// Fallback (tiny workspace): edge-parallel atomic kernel.
__global__ __launch_bounds__(256) void spmm_atomic_kernel(
    const float* __restrict__ x,
    const int*   __restrict__ adj_rows,
    const int*   __restrict__ adj_cols,
    const float* __restrict__ adj_vals,
    const int*   __restrict__ idx_p,
    float*       __restrict__ out)
{
    const long long idx = (long long)idx_p[0];
    const int*   rows = adj_rows + idx * (long long)N_EDGES;
    const int*   cols = adj_cols + idx * (long long)N_EDGES;
    const float* vals = adj_vals + idx * (long long)N_EDGES;

    long long tt = (long long)blockIdx.x * blockDim.x + threadIdx.x;
    long long e  = tt >> 5;
    int       f4 = (int)(tt & 31);
    if (e >= N_EDGES) return;

    const int   r = rows[e];
    const int   c = cols[e];
    const float v = vals[e];
    const float4 xv =
        *reinterpret_cast<const float4*>(x + (long long)c * D_FEAT + f4 * 4);
    float* o = out + (long long)r * D_FEAT + f4 * 4;
    unsafeAtomicAdd(o + 0, v * xv.x);
    unsafeAtomicAdd(o + 1, v * xv.y);
    unsafeAtomicAdd(o + 2, v * xv.z);
    unsafeAtomicAdd(o + 3, v * xv.w);
}

extern "C" void kernel_launch(void* const* d_in, const int* in_sizes, int n_in,
                              void* d_out, int out_size, void* d_ws, size_t ws_size,
                              hipStream_t stream) {
    const float* x        = (const float*)d_in[0];
    const int*   adj_rows = (const int*)  d_in[1];
    const int*   adj_cols = (const int*)  d_in[2];
    const float* adj_vals = (const float*)d_in[3];
    const int*   idx_p    = (const int*)  d_in[4];
    float*       out      = (float*)d_out;

    // Workspace layout (4-byte elements):
    //   bhist   : NB      \ one memset covers
    //   bcursor : NB      /  these two
    //   bptr    : NB+1
    //   pad     : to multiple-of-4 ints (16B-align pairs & xb)
    //   pairs   : N_EDGES int2              (25.6 MB)
    //   xb      : N_NODES*D_FEAT bf16       (25.6 MB)
    const size_t n_meta_raw = (size_t)NB * 3 + 1;
    const size_t n_meta     = (n_meta_raw + 3) & ~(size_t)3;
    const size_t need       = (n_meta + (size_t)2 * N_EDGES) * 4
                            + (size_t)N_NODES * D_FEAT * 2;

    if (ws_size < need) {
        hipMemsetAsync(out, 0, (size_t)out_size * sizeof(float), stream);
        const long long total_threads = (long long)N_EDGES * 32;
        const int block = 256;
        const long long grid = (total_threads + block - 1) / block;
        spmm_atomic_kernel<<<(dim3)(unsigned)grid, block, 0, stream>>>(
            x, adj_rows, adj_cols, adj_vals, idx_p, out);
        return;
    }

    int*   bhist   = (int*)d_ws;
    int*   bcursor = bhist + NB;
    int*   bptr    = bcursor + NB;
    int2*  pairs   = (int2*)((int*)d_ws + n_meta);
    uint4* xb      = (uint4*)((int*)d_ws + n_meta + (size_t)2 * N_EDGES);

    hipMemsetAsync(d_ws, 0, (size_t)(2 * NB) * sizeof(int), stream);

    cvt_bhist_kernel<<<HIST_BLOCKS + CVT_BLOCKS, 256, 0, stream>>>(
        x, xb, adj_rows, idx_p, bhist);
    partition_kernel<<<P3_GRID, P3_THREADS, 0, stream>>>(
        adj_rows, adj_cols, adj_vals, idx_p, bhist, bcursor, bptr, pairs);
    sort_spmm_kernel<<<NB, 1024, 0, stream>>>(xb, bptr, pairs, out);
}

// Round 13
// 196.242 us; speedup vs baseline: 1.7583x; 1.1260x over previous
//
#include <hip/hip_runtime.h>

#define N_NODES 100000
#define N_EDGES 3200000
#define D_FEAT  128

#define RPB 128                              // rows per bucket (row >> 7)
#define NB ((N_NODES + RPB - 1) / RPB)       // 782 buckets
#define P3_THREADS 512
#define P3_EPT 32                            // edges per thread in partition
#define P3_TILE (P3_THREADS * P3_EPT)        // 16384 edges per partition block
#define P3_GRID ((N_EDGES + P3_TILE - 1) / P3_TILE)   // 196

#define NS 25                                // col slices (col >> 12, 1MB bf16 each)
#define NCELL (RPB * NS)                     // 3200 sort cells
#define CAP 4608                             // staging cap & fixed stride (mean 4092, max~4330)

#define CVT_B 1024                           // cvt-role blocks in fused kernel

// mid-path (R12) config
#define HIST_BLOCKS 768
#define CVT_BLOCKS 1536

typedef int   nt_i2 __attribute__((ext_vector_type(2)));
typedef float nt_f4 __attribute__((ext_vector_type(4)));

// ---------------------------------------------------------------------------
// Pipeline (R13): FIXED-STRIDE bucket regions kill the hist/scan machinery.
//   0) memset bcursor (782 ints).
//   1) part_cvt (FUSED, one launch): blocks [0,196) counting-partition edges
//      into pairs[b*CAP + ...] (per-block LDS count -> one global reservation
//      per (block,bucket) -> place); blocks [196,1220) convert x -> bf16.
//      The two jobs are independent and now run CONCURRENTLY.
//   2) sort_spmm<FS=1>: per-bucket 2-level (row, col>>12) LDS counting sort
//      (n = bcursor[b], base = b*CAP) + SpMM: 16-lane group per row, LDS
//      same-addr broadcast, f32 reg accum, one 512B NT row write.
// R5-R12 lesson: sort_spmm pins the ~5.6 TB/s random-256B request ceiling
// (147us, FETCH ~434MB, invariant across 4 structures) — only the ~74us of
// serialized preprocessing was left to attack.
// Fallbacks: mid path = R12 (hist+scan+bptr) if ws too small for fixed
// stride; last = edge-parallel atomics.
// ---------------------------------------------------------------------------

__device__ inline unsigned bf16rne(float f) {
    unsigned u = __float_as_uint(f);
    u += 0x7fffu + ((u >> 16) & 1u);
    return u >> 16;
}
__device__ inline unsigned pack2(float lo, float hi) {
    return bf16rne(lo) | (bf16rne(hi) << 16);
}

// ============================ FAST (FS) PATH ================================

// Fused: partition (blocks < P3_GRID) + x->bf16 convert (rest).
__global__ __launch_bounds__(P3_THREADS) void part_cvt_kernel(
    const float* __restrict__ x, uint4* __restrict__ xb,
    const int* __restrict__ adj_rows, const int* __restrict__ adj_cols,
    const float* __restrict__ adj_vals, const int* __restrict__ idx_p,
    int* __restrict__ bcursor, int2* __restrict__ pairs)
{
    if (blockIdx.x >= P3_GRID) {
        // ---- cvt role ----
        const int total = N_NODES * D_FEAT / 8;
        for (int i = (blockIdx.x - P3_GRID) * P3_THREADS + (int)threadIdx.x;
             i < total; i += CVT_B * P3_THREADS) {
            const float4 a = reinterpret_cast<const float4*>(x)[2 * i];
            const float4 b = reinterpret_cast<const float4*>(x)[2 * i + 1];
            uint4 o;
            o.x = pack2(a.x, a.y);
            o.y = pack2(a.z, a.w);
            o.z = pack2(b.x, b.y);
            o.w = pack2(b.z, b.w);
            xb[i] = o;
        }
        return;
    }

    // ---- partition role: fixed-stride bucket regions ----
    __shared__ int lcnt[NB];
    __shared__ int lbase[NB];
    const int t = (int)threadIdx.x;
    const long long idx = (long long)idx_p[0];
    const int*   rows = adj_rows + idx * (long long)N_EDGES;
    const int*   cols = adj_cols + idx * (long long)N_EDGES;
    const float* vals = adj_vals + idx * (long long)N_EDGES;
    const int tile = blockIdx.x * P3_TILE;

    for (int i = t; i < NB; i += P3_THREADS) lcnt[i] = 0;
    __syncthreads();

    int rc[P3_EPT];                       // cached row (or -1)
#pragma unroll
    for (int k = 0; k < P3_EPT; ++k) {
        const int e = tile + k * P3_THREADS + t;
        rc[k] = (e < N_EDGES) ? rows[e] : -1;
        if (rc[k] >= 0) atomicAdd(&lcnt[rc[k] >> 7], 1);
    }
    __syncthreads();

    for (int i = t; i < NB; i += P3_THREADS) {
        const int c = lcnt[i];
        lbase[i] = c ? atomicAdd(&bcursor[i], c) : 0;   // relative to b*CAP
        lcnt[i]  = 0;
    }
    __syncthreads();

#pragma unroll
    for (int k = 0; k < P3_EPT; ++k) {
        const int r = rc[k];
        if (r >= 0) {
            const int e = tile + k * P3_THREADS + t;
            const int b = r >> 7;
            const int off = lbase[b] + atomicAdd(&lcnt[b], 1);
            if (off < CAP)
                pairs[(size_t)b * CAP + off] =
                    make_int2(((r & (RPB - 1)) << 24) | cols[e],
                              __float_as_int(vals[e]));
        }
    }
}

// ======================== SHARED sort+spmm KERNEL ===========================
// FS=1: base = b*CAP, n = bcursor[b].  FS=0: base = bptr[b], n from bptr.
template <bool FS>
__global__ __launch_bounds__(1024) void sort_spmm_kernel(
    const uint4* __restrict__ xb, const int* __restrict__ meta,
    const int2* __restrict__ pairs, float* __restrict__ out)
{
    __shared__ int2 staged[CAP];          // 36,864 B, sorted by (row, colslice)
    __shared__ int  cellptr[NCELL];       // 12,800 B: counts -> scan -> cursors
    __shared__ int  rs[RPB + 1];          //    516 B: per-row start
    __shared__ int  scan[1024];           //  4,096 B
    const int b = blockIdx.x;
    const int t = (int)threadIdx.x;
    size_t base;
    int n;
    if constexpr (FS) {
        base = (size_t)b * CAP;
        n    = min(meta[b], CAP);
    } else {
        base = (size_t)meta[b];
        n    = meta[b + 1] - (int)base;
    }

    for (int i = t; i < NCELL; i += 1024) cellptr[i] = 0;
    __syncthreads();

    // Pass A: count cells (key = row_lo * NS + col_slice).
    for (int i = t; i < n; i += 1024) {
        const int2 p = pairs[base + i];
        const int row = ((unsigned)p.x) >> 24;
        const int col = p.x & 0xFFFFFF;
        atomicAdd(&cellptr[row * NS + (col >> 12)], 1);
    }
    __syncthreads();

    // Exclusive scan over NCELL cells: thread t owns cells [4t, 4t+4).
    const int i0 = t * 4;
    int v0 = 0, v1 = 0, v2 = 0, v3 = 0;
    if (i0 + 0 < NCELL) v0 = cellptr[i0 + 0];
    if (i0 + 1 < NCELL) v1 = cellptr[i0 + 1];
    if (i0 + 2 < NCELL) v2 = cellptr[i0 + 2];
    if (i0 + 3 < NCELL) v3 = cellptr[i0 + 3];
    const int s = v0 + v1 + v2 + v3;
    scan[t] = s;
    __syncthreads();
    for (int off = 1; off < 1024; off <<= 1) {
        int u = (t >= off) ? scan[t - off] : 0;
        __syncthreads();
        scan[t] += u;
        __syncthreads();
    }
    int run = scan[t] - s;                // exclusive prefix for cell i0
    if (i0 + 0 < NCELL) { cellptr[i0 + 0] = run; run += v0; }
    if (i0 + 1 < NCELL) { cellptr[i0 + 1] = run; run += v1; }
    if (i0 + 2 < NCELL) { cellptr[i0 + 2] = run; run += v2; }
    if (i0 + 3 < NCELL) { cellptr[i0 + 3] = run; run += v3; }
    __syncthreads();

    // Row starts (before cellptr mutates into cursors).
    if (t < RPB) rs[t] = cellptr[t * NS];
    if (t == 0)  rs[RPB] = n;
    __syncthreads();

    // Pass B: scatter into LDS sorted by (row, colslice). NT load (last use).
    for (int i = t; i < n; i += 1024) {
        const nt_i2 pr = __builtin_nontemporal_load(
            reinterpret_cast<const nt_i2*>(pairs + base + i));
        const int w0 = pr[0];
        const int row = ((unsigned)w0) >> 24;
        const int col = w0 & 0xFFFFFF;
        const int pos = atomicAdd(&cellptr[row * NS + (col >> 12)], 1);
        if (pos < CAP) staged[pos] = make_int2(w0, pr[1]);
    }
    __syncthreads();

    // SpMM: group g of wave w handles rows (w*4+g) + 64*k, k=0,1.
    const int w    = t >> 6;
    const int lane = t & 63;
    const int g    = lane >> 4;          // group within wave
    const int sl   = lane & 15;          // 8-feature slot
    const int grp  = w * 4 + g;          // 0..63

    for (int k = 0; k < 2; ++k) {
        const int r   = grp + 64 * k;    // 0..127
        const int row = b * RPB + r;
        if (row >= N_NODES) break;
        const int s0 = rs[r];
        const int e0 = rs[r + 1];

        float4 a0 = make_float4(0.f, 0.f, 0.f, 0.f);
        float4 a1 = make_float4(0.f, 0.f, 0.f, 0.f);
        for (int j = s0; j < e0; ++j) {
            const int2  p   = staged[j];          // same-addr LDS broadcast
            const int   col = p.x & 0xFFFFFF;
            const float vj  = __int_as_float(p.y);
            const uint4 wv  = xb[(size_t)col * (D_FEAT / 8) + sl];
            a0.x += vj * __uint_as_float(wv.x << 16);
            a0.y += vj * __uint_as_float(wv.x & 0xffff0000u);
            a0.z += vj * __uint_as_float(wv.y << 16);
            a0.w += vj * __uint_as_float(wv.y & 0xffff0000u);
            a1.x += vj * __uint_as_float(wv.z << 16);
            a1.y += vj * __uint_as_float(wv.z & 0xffff0000u);
            a1.z += vj * __uint_as_float(wv.w << 16);
            a1.w += vj * __uint_as_float(wv.w & 0xffff0000u);
        }
        float* op = out + (size_t)row * D_FEAT + sl * 8;
        nt_f4 o0 = {a0.x, a0.y, a0.z, a0.w};
        nt_f4 o1 = {a1.x, a1.y, a1.z, a1.w};
        __builtin_nontemporal_store(o0, reinterpret_cast<nt_f4*>(op));
        __builtin_nontemporal_store(o1, reinterpret_cast<nt_f4*>(op) + 1);
    }
}

// ============================ MID (R12) PATH ================================

__global__ __launch_bounds__(256) void cvt_bhist_kernel(
    const float* __restrict__ x, uint4* __restrict__ xb,
    const int* __restrict__ adj_rows, const int* __restrict__ idx_p,
    int* __restrict__ bhist)
{
    __shared__ int lh[NB];
    if (blockIdx.x < HIST_BLOCKS) {
        for (int i = threadIdx.x; i < NB; i += 256) lh[i] = 0;
        __syncthreads();
        const long long idx = (long long)idx_p[0];
        const int* rows = adj_rows + idx * (long long)N_EDGES;
        for (int e = blockIdx.x * 256 + threadIdx.x; e < N_EDGES;
             e += HIST_BLOCKS * 256)
            atomicAdd(&lh[rows[e] >> 7], 1);
        __syncthreads();
        for (int i = threadIdx.x; i < NB; i += 256)
            if (lh[i]) atomicAdd(&bhist[i], lh[i]);
    } else {
        const int total = N_NODES * D_FEAT / 8;
        for (int i = (blockIdx.x - HIST_BLOCKS) * 256 + threadIdx.x; i < total;
             i += CVT_BLOCKS * 256) {
            const float4 a = reinterpret_cast<const float4*>(x)[2 * i];
            const float4 b = reinterpret_cast<const float4*>(x)[2 * i + 1];
            uint4 o;
            o.x = pack2(a.x, a.y);
            o.y = pack2(a.z, a.w);
            o.z = pack2(b.x, b.y);
            o.w = pack2(b.z, b.w);
            xb[i] = o;
        }
    }
}

__global__ __launch_bounds__(P3_THREADS) void partition_kernel(
    const int* __restrict__ adj_rows, const int* __restrict__ adj_cols,
    const float* __restrict__ adj_vals, const int* __restrict__ idx_p,
    const int* __restrict__ bhist, int* __restrict__ bcursor,
    int* __restrict__ bptr, int2* __restrict__ pairs)
{
    __shared__ int lcnt[NB];
    __shared__ int lbase[NB];
    __shared__ int lbptr[NB];
    __shared__ int sscan[P3_THREADS];
    const int t = (int)threadIdx.x;

    const int e0 = 2 * t, e1 = 2 * t + 1;
    const int v0 = (e0 < NB) ? bhist[e0] : 0;
    const int v1 = (e1 < NB) ? bhist[e1] : 0;
    const int ss = v0 + v1;
    sscan[t] = ss;
    if (t < NB) lcnt[t] = 0;
    if (t + P3_THREADS < NB) lcnt[t + P3_THREADS] = 0;
    __syncthreads();
    for (int off = 1; off < P3_THREADS; off <<= 1) {
        int u = (t >= off) ? sscan[t - off] : 0;
        __syncthreads();
        sscan[t] += u;
        __syncthreads();
    }
    const int pre = sscan[t] - ss;
    if (e0 < NB) lbptr[e0] = pre;
    if (e1 < NB) lbptr[e1] = pre + v0;
    if (blockIdx.x == 0) {
        if (e0 < NB) bptr[e0] = pre;
        if (e1 < NB) bptr[e1] = pre + v0;
        if (t == P3_THREADS - 1) bptr[NB] = sscan[t];
    }
    __syncthreads();

    const long long idx = (long long)idx_p[0];
    const int*   rows = adj_rows + idx * (long long)N_EDGES;
    const int*   cols = adj_cols + idx * (long long)N_EDGES;
    const float* vals = adj_vals + idx * (long long)N_EDGES;
    const int tile = blockIdx.x * P3_TILE;

    int rc[P3_EPT];
#pragma unroll
    for (int k = 0; k < P3_EPT; ++k) {
        const int e = tile + k * P3_THREADS + t;
        rc[k] = (e < N_EDGES) ? rows[e] : -1;
        if (rc[k] >= 0) atomicAdd(&lcnt[rc[k] >> 7], 1);
    }
    __syncthreads();

    for (int i = t; i < NB; i += P3_THREADS) {
        const int c = lcnt[i];
        lbase[i] = c ? atomicAdd(&bcursor[i], c) : 0;
        lcnt[i]  = 0;
    }
    __syncthreads();

#pragma unroll
    for (int k = 0; k < P3_EPT; ++k) {
        const int r = rc[k];
        if (r >= 0) {
            const int e = tile + k * P3_THREADS + t;
            const int b = r >> 7;
            const int pos = lbptr[b] + lbase[b] + atomicAdd(&lcnt[b], 1);
            pairs[pos] = make_int2(((r & (RPB - 1)) << 24) | cols[e],
                                   __float_as_int(vals[e]));
        }
    }
}

// =========================== LAST FALLBACK ==================================

__global__ __launch_bounds__(256) void spmm_atomic_kernel(
    const float* __restrict__ x,
    const int*   __restrict__ adj_rows,
    const int*   __restrict__ adj_cols,
    const float* __restrict__ adj_vals,
    const int*   __restrict__ idx_p,
    float*       __restrict__ out)
{
    const long long idx = (long long)idx_p[0];
    const int*   rows = adj_rows + idx * (long long)N_EDGES;
    const int*   cols = adj_cols + idx * (long long)N_EDGES;
    const float* vals = adj_vals + idx * (long long)N_EDGES;

    long long tt = (long long)blockIdx.x * blockDim.x + threadIdx.x;
    long long e  = tt >> 5;
    int       f4 = (int)(tt & 31);
    if (e >= N_EDGES) return;

    const int   r = rows[e];
    const int   c = cols[e];
    const float v = vals[e];
    const float4 xv =
        *reinterpret_cast<const float4*>(x + (long long)c * D_FEAT + f4 * 4);
    float* o = out + (long long)r * D_FEAT + f4 * 4;
    unsafeAtomicAdd(o + 0, v * xv.x);
    unsafeAtomicAdd(o + 1, v * xv.y);
    unsafeAtomicAdd(o + 2, v * xv.z);
    unsafeAtomicAdd(o + 3, v * xv.w);
}

extern "C" void kernel_launch(void* const* d_in, const int* in_sizes, int n_in,
                              void* d_out, int out_size, void* d_ws, size_t ws_size,
                              hipStream_t stream) {
    const float* x        = (const float*)d_in[0];
    const int*   adj_rows = (const int*)  d_in[1];
    const int*   adj_cols = (const int*)  d_in[2];
    const float* adj_vals = (const float*)d_in[3];
    const int*   idx_p    = (const int*)  d_in[4];
    float*       out      = (float*)d_out;

    const size_t xb_bytes = (size_t)N_NODES * D_FEAT * 2;

    // --- FS layout: bcursor NB | pad | pairs NB*CAP int2 | xb ---
    const size_t fs_meta  = ((size_t)NB + 3) & ~(size_t)3;
    const size_t fs_pairs = (size_t)NB * CAP * 2;           // ints
    const size_t need_fs  = (fs_meta + fs_pairs) * 4 + xb_bytes;

    // --- mid (R12) layout: bhist NB | bcursor NB | bptr NB+1 | pad | pairs | xb
    const size_t mid_meta_raw = (size_t)NB * 3 + 1;
    const size_t mid_meta     = (mid_meta_raw + 3) & ~(size_t)3;
    const size_t need_mid     = (mid_meta + (size_t)2 * N_EDGES) * 4 + xb_bytes;

    if (ws_size >= need_fs) {
        int*   bcursor = (int*)d_ws;
        int2*  pairs   = (int2*)((int*)d_ws + fs_meta);
        uint4* xb      = (uint4*)((int*)d_ws + fs_meta + fs_pairs);

        hipMemsetAsync(bcursor, 0, (size_t)NB * sizeof(int), stream);
        part_cvt_kernel<<<P3_GRID + CVT_B, P3_THREADS, 0, stream>>>(
            x, xb, adj_rows, adj_cols, adj_vals, idx_p, bcursor, pairs);
        sort_spmm_kernel<true><<<NB, 1024, 0, stream>>>(
            xb, bcursor, pairs, out);
        return;
    }

    if (ws_size >= need_mid) {
        int*   bhist   = (int*)d_ws;
        int*   bcursor = bhist + NB;
        int*   bptr    = bcursor + NB;
        int2*  pairs   = (int2*)((int*)d_ws + mid_meta);
        uint4* xb      = (uint4*)((int*)d_ws + mid_meta + (size_t)2 * N_EDGES);

        hipMemsetAsync(d_ws, 0, (size_t)(2 * NB) * sizeof(int), stream);
        cvt_bhist_kernel<<<HIST_BLOCKS + CVT_BLOCKS, 256, 0, stream>>>(
            x, xb, adj_rows, idx_p, bhist);
        partition_kernel<<<P3_GRID, P3_THREADS, 0, stream>>>(
            adj_rows, adj_cols, adj_vals, idx_p, bhist, bcursor, bptr, pairs);
        sort_spmm_kernel<false><<<NB, 1024, 0, stream>>>(
            xb, bptr, pairs, out);
        return;
    }

    // Last fallback: edge-parallel atomics.
    hipMemsetAsync(out, 0, (size_t)out_size * sizeof(float), stream);
    const long long total_threads = (long long)N_EDGES * 32;
    const int block = 256;
    const long long grid = (total_threads + block - 1) / block;
    spmm_atomic_kernel<<<(dim3)(unsigned)grid, block, 0, stream>>>(
        x, adj_rows, adj_cols, adj_vals, idx_p, out);
}